// Round 7
// baseline (323.854 us; speedup 1.0000x reference)
//
#include <hip/hip_runtime.h>
#include <hip/hip_bf16.h>
#include <hip/hip_cooperative_groups.h>

namespace cg = cooperative_groups;

typedef unsigned short u16;
typedef unsigned int u32;
typedef __attribute__((ext_vector_type(8))) short short8;
typedef __attribute__((ext_vector_type(4))) float floatx4;

#define NU 16384
#define DIM 256
#define AMS 208               // Am LDS row stride (u16)
#define XST 264               // strip / Y LDS row stride (u16)
#define CTS 84                // Ct transpose stride (u16)

// ws layout (u16 offsets)
#define XHo 0u
#define XLo 4194304u
#define ST0 8388608u
#define STROW 16512u          // 64 guard + 16384 + 64 guard
#define STMAT 4227072u        // 256 * STROW
#define WH0o 21069824u        // ST0 + 3*STMAT
#define WL0o 21135360u
#define WRo  21200896u        // 3 mats x 65536

__device__ __forceinline__ float bup(u16 u) {
  return __uint_as_float(((u32)u) << 16);
}
__device__ __forceinline__ u16 bfrn(float v) {           // round-nearest-even
  u32 u = __float_as_uint(v);
  return (u16)((u + 0x7fffu + ((u >> 16) & 1u)) >> 16);
}

// ---------------------------------------------------------------------------
// Single cooperative kernel. grid 256 x 512 (1 block/CU).
// A: x-split (hi=RNE, lo) -> ws + LDS strip; weight imaging; S^T guards.
// B: S1..S3 = x@Wr (strip-h A-frags, global W-frags, S^T epilogue);
//    y = x@W_att split 3-MFMA -> Y kept in LDS.
// C: P = Y.Xwin^T (split), reg softmax, masked A-image, banded aggregation
//    (direct-global S^T B-frags), cross-wave log_softmax.
// ---------------------------------------------------------------------------
__global__ __launch_bounds__(512, 2) void fused_all(
    const float* __restrict__ x, const int* __restrict__ spk,
    const float* __restrict__ wat, const float* __restrict__ wpr,
    const float* __restrict__ wsu, const float* __restrict__ wsm,
    const float* __restrict__ wdf,
    float* __restrict__ out, u16* __restrict__ ws)
{
  __shared__ __align__(16) u16 A_[2 * 64 * XST];   // strip h|l -> later Yh|Yl
  __shared__ __align__(16) u16 B_[256 * CTS];      // Ct | X-window stg | Ac
  __shared__ __align__(16) u16 Am[64 * AMS];
  __shared__ int spkw[192];
  __shared__ float prt[64][2], prs[64][2];
  __shared__ float red[64][8];

  const int t    = threadIdx.x;
  const int b    = blockIdx.x;
  const int w    = t >> 6;
  const int ln   = t & 15;
  const int quad = (t & 63) >> 4;
  const int q8   = quad * 8;
  const int row0 = b * 64;
  const int i0   = row0;

  cg::grid_group grid = cg::this_grid();

  if (t < 192) spkw[t] = spk[min(max(i0 - 64 + t, 0), NU - 1)];

  // ================= Phase A =================
#pragma unroll
  for (int cc = 0; cc < 4; ++cc) {
    int e = t * 8 + cc * 4096;                 // 0..16383
    int row = e >> 8, col = e & 255;
    const float* xp = x + (size_t)(row0 + row) * DIM + col;
    float4 v0 = *(const float4*)(xp);
    float4 v1 = *(const float4*)(xp + 4);
    float a[8] = {v0.x, v0.y, v0.z, v0.w, v1.x, v1.y, v1.z, v1.w};
    u16 h[8], l[8];
#pragma unroll
    for (int q = 0; q < 8; ++q) {
      h[q] = bfrn(a[q]);
      l[q] = bfrn(a[q] - bup(h[q]));
    }
    size_t go = (size_t)(row0 + row) * DIM + col;
    *(uint4*)(ws + XHo + go) = *(const uint4*)h;
    *(uint4*)(ws + XHo + go + 4) = *(const uint4*)(h + 4);  // h is 8 u16 = 1 uint4... split
    *(uint4*)(ws + XLo + go) = *(const uint4*)l;
    *(uint4*)(ws + XLo + go + 4) = *(const uint4*)(l + 4);
    *(uint4*)(A_ + row * XST + col)     = *(const uint4*)h;
    *(uint4*)(A_ + 64 * XST + row * XST + col) = *(const uint4*)l;
  }
  if (b < 16) {                                 // weight imaging
    const int mat = b >> 2;
    const int s = (b & 3) * 2 + (t >> 8);
    const int n = t & 255;
    const float* Wa = (mat == 0) ? wat : (mat == 1) ? wpr : (mat == 2) ? wsm : wsu;
    const float* Wb = (mat == 0) ? wat : (mat == 1) ? wsu : (mat == 2) ? wdf : wdf;
    const float c1  = (mat == 0) ? 0.f : (mat == 3) ? 1.f : -1.f;
    u16 hbuf[32], lbuf[32];
#pragma unroll 8
    for (int k = 0; k < 32; ++k) {
      float v = Wa[(s * 32 + k) * 256 + n] + c1 * Wb[(s * 32 + k) * 256 + n];
      hbuf[k] = bfrn(v);
      if (mat == 0) lbuf[k] = bfrn(v - bup(hbuf[k]));
    }
    u16* dh = ws + ((mat == 0) ? WH0o : (WRo + (size_t)(mat - 1) * 65536))
               + (size_t)s * 8192 + n * 32;
#pragma unroll
    for (int p = 0; p < 4; ++p) *(uint4*)(dh + p * 8) = ((const uint4*)hbuf)[p];
    if (mat == 0) {
      u16* dl = ws + WL0o + (size_t)s * 8192 + n * 32;
#pragma unroll
      for (int p = 0; p < 4; ++p) *(uint4*)(dl + p * 8) = ((const uint4*)lbuf)[p];
    }
  }
  if (b >= 32 && b < 80) {                      // S^T guard zeroing
    int g = (b - 32) * 512 + t;                 // 0..24575
    int r = g >> 13, rem = g & 8191;
    int d = rem >> 5, p = rem & 31;
    size_t base = ST0 + (size_t)r * STMAT + (size_t)d * STROW;
    size_t off = (p < 16) ? (base + p * 4) : (base + 16448 + (p - 16) * 4);
    *(ushort4*)(ws + off) = make_ushort4(0, 0, 0, 0);
  }
  __threadfence();
  grid.sync();

  // ================= Phase B =================
  const int mg = (w & 1) * 2;                   // m-frags mg, mg+1
  const int ng = (w >> 1) * 4;                  // nt-frags ng..ng+3

  // ---- S1..S3 ----
  for (int mat = 0; mat < 3; ++mat) {
    floatx4 acc[2][4];
#pragma unroll
    for (int mi = 0; mi < 2; ++mi)
#pragma unroll
      for (int nf = 0; nf < 4; ++nf) acc[mi][nf] = (floatx4){0.f, 0.f, 0.f, 0.f};
    for (int s = 0; s < 8; ++s) {
      short8 a0 = *(const short8*)(A_ + ((mg + 0) * 16 + ln) * XST + s * 32 + q8);
      short8 a1 = *(const short8*)(A_ + ((mg + 1) * 16 + ln) * XST + s * 32 + q8);
#pragma unroll
      for (int nf = 0; nf < 4; ++nf) {
        short8 bh = *(const short8*)(ws + WRo + (size_t)mat * 65536
                     + (size_t)s * 8192 + ((ng + nf) * 16 + ln) * 32 + q8);
        acc[0][nf] = __builtin_amdgcn_mfma_f32_16x16x32_bf16(a0, bh, acc[0][nf], 0, 0, 0);
        acc[1][nf] = __builtin_amdgcn_mfma_f32_16x16x32_bf16(a1, bh, acc[1][nf], 0, 0, 0);
      }
    }
    __syncthreads();                             // B_ free (prev copy-out done)
#pragma unroll
    for (int mi = 0; mi < 2; ++mi)
#pragma unroll
      for (int nf = 0; nf < 4; ++nf) {
        int col = (ng + nf) * 16 + ln;
        ushort4 pk = make_ushort4(bfrn(acc[mi][nf][0]), bfrn(acc[mi][nf][1]),
                                  bfrn(acc[mi][nf][2]), bfrn(acc[mi][nf][3]));
        *(ushort4*)(B_ + col * CTS + (mg + mi) * 16 + quad * 4) = pk;
      }
    __syncthreads();
    u16* STm = ws + ST0 + (size_t)mat * STMAT;
#pragma unroll
    for (int cc = 0; cc < 4; ++cc) {
      int c = t + 512 * cc;                      // 0..2047
      int d = c >> 3, part = c & 7;
      *(uint4*)(STm + (size_t)d * STROW + 64 + row0 + part * 8) =
          *(const uint4*)(B_ + d * CTS + part * 8);
    }
  }

  // ---- y = x @ W_att (split 3-MFMA) ----
  {
    floatx4 acc[2][4];
#pragma unroll
    for (int mi = 0; mi < 2; ++mi)
#pragma unroll
      for (int nf = 0; nf < 4; ++nf) acc[mi][nf] = (floatx4){0.f, 0.f, 0.f, 0.f};
    for (int s = 0; s < 8; ++s) {
      short8 ah[2], al[2];
#pragma unroll
      for (int mi = 0; mi < 2; ++mi) {
        ah[mi] = *(const short8*)(A_ + ((mg + mi) * 16 + ln) * XST + s * 32 + q8);
        al[mi] = *(const short8*)(A_ + 64 * XST + ((mg + mi) * 16 + ln) * XST + s * 32 + q8);
      }
#pragma unroll
      for (int nf = 0; nf < 4; ++nf) {
        size_t off = (size_t)s * 8192 + ((ng + nf) * 16 + ln) * 32 + q8;
        short8 bh = *(const short8*)(ws + WH0o + off);
        short8 bl = *(const short8*)(ws + WL0o + off);
#pragma unroll
        for (int mi = 0; mi < 2; ++mi) {
          acc[mi][nf] = __builtin_amdgcn_mfma_f32_16x16x32_bf16(ah[mi], bh, acc[mi][nf], 0, 0, 0);
          acc[mi][nf] = __builtin_amdgcn_mfma_f32_16x16x32_bf16(ah[mi], bl, acc[mi][nf], 0, 0, 0);
          acc[mi][nf] = __builtin_amdgcn_mfma_f32_16x16x32_bf16(al[mi], bh, acc[mi][nf], 0, 0, 0);
        }
      }
    }
    __syncthreads();                             // strip reads complete
    // Yh/Yl overwrite the strip region
#pragma unroll
    for (int mi = 0; mi < 2; ++mi)
#pragma unroll
      for (int nf = 0; nf < 4; ++nf) {
        int col = (ng + nf) * 16 + ln;
#pragma unroll
        for (int r = 0; r < 4; ++r) {
          int row = (mg + mi) * 16 + quad * 4 + r;
          float y = acc[mi][nf][r];
          u16 hh = bfrn(y);
          A_[row * XST + col] = hh;
          A_[64 * XST + row * XST + col] = bfrn(y - bup(hh));
        }
      }
  }
  __threadfence();
  grid.sync();

  // ================= Phase C =================
  const int mw   = w & 3;                        // m-frag (16 rows)
  const int half = w >> 2;                       // window col half (96 each)

  // ---- P = Y . Xwin^T ----
  floatx4 accP[6];
#pragma unroll
  for (int cc = 0; cc < 6; ++cc) accP[cc] = (floatx4){0.f, 0.f, 0.f, 0.f};

  for (int kd = 0; kd < DIM; kd += 32) {
#pragma unroll
    for (int cc = 0; cc < 3; ++cc) {             // stage X window 192x32 hi/lo
      int idx = t + 512 * cc;                    // 0..1535
      int buf = (idx >= 768) ? 1 : 0;
      int e   = idx - buf * 768;
      int row = e >> 2, c8 = (e & 3) * 8;
      int jc  = min(max(i0 + row - 64, 0), NU - 1);
      *(uint4*)(B_ + buf * 6144 + row * 32 + c8) =
          *(const uint4*)(ws + (buf ? XLo : XHo) + (size_t)jc * 256 + kd + c8);
    }
    __syncthreads();

    short8 yh8 = *(const short8*)(A_ + (mw * 16 + ln) * XST + kd + q8);
    short8 yl8 = *(const short8*)(A_ + 64 * XST + (mw * 16 + ln) * XST + kd + q8);
#pragma unroll
    for (int cc = 0; cc < 6; ++cc) {
      int xrow = half * 96 + cc * 16 + ln;
      short8 xbh = *(const short8*)(B_ + xrow * 32 + q8);
      short8 xbl = *(const short8*)(B_ + 6144 + xrow * 32 + q8);
      accP[cc] = __builtin_amdgcn_mfma_f32_16x16x32_bf16(yh8, xbh, accP[cc], 0, 0, 0);
      accP[cc] = __builtin_amdgcn_mfma_f32_16x16x32_bf16(yh8, xbl, accP[cc], 0, 0, 0);
      accP[cc] = __builtin_amdgcn_mfma_f32_16x16x32_bf16(yl8, xbh, accP[cc], 0, 0, 0);
    }
    __syncthreads();
  }

  // ---- softmax in registers ----
  int  c_of[6];
  bool vj[6];
#pragma unroll
  for (int cc = 0; cc < 6; ++cc) {
    c_of[cc] = half * 96 + cc * 16 + ln;
    int j = i0 + c_of[cc] - 64;
    vj[cc] = (j >= 0) && (j < NU);
  }
#pragma unroll
  for (int r = 0; r < 4; ++r) {
    int row = mw * 16 + quad * 4 + r;
    float mx = -3.4e38f;
#pragma unroll
    for (int cc = 0; cc < 6; ++cc) {
      int rel = c_of[cc] - row;
      bool inb = (rel >= 0) && (rel < 128);
      if (inb) mx = fmaxf(mx, vj[cc] ? accP[cc][r] : 0.f);
    }
#pragma unroll
    for (int o = 1; o < 16; o <<= 1) mx = fmaxf(mx, __shfl_xor(mx, o));
    if (ln == 0) prt[row][half] = mx;
  }
  __syncthreads();
#pragma unroll
  for (int r = 0; r < 4; ++r) {
    int row = mw * 16 + quad * 4 + r;
    float gm = fmaxf(prt[row][0], prt[row][1]);
    float s = 0.f;
#pragma unroll
    for (int cc = 0; cc < 6; ++cc) {
      int rel = c_of[cc] - row;
      bool inb = (rel >= 0) && (rel < 128);
      float vv = vj[cc] ? accP[cc][r] : 0.f;
      float e  = inb ? __expf(vv - gm) : 0.f;
      s += e;                                    // padded-slot denominator
      accP[cc][r] = (inb && vj[cc]) ? e : 0.f;   // masked numerator
    }
#pragma unroll
    for (int o = 1; o < 16; o <<= 1) s += __shfl_xor(s, o);
    if (ln == 0) prs[row][half] = s;
  }
  __syncthreads();
#pragma unroll
  for (int r = 0; r < 4; ++r) {
    int row = mw * 16 + quad * 4 + r;
    float inv = 1.f / (prs[row][0] + prs[row][1]);
#pragma unroll
    for (int cc = 0; cc < 6; ++cc)
      Am[row * AMS + c_of[cc]] = bfrn(accP[cc][r] * inv);
  }
  __syncthreads();

  // ---- aggregation ----
  const int n0 = w * 32;
  floatx4 acc2[4][2];
#pragma unroll
  for (int m = 0; m < 4; ++m)
#pragma unroll
    for (int nt = 0; nt < 2; ++nt) acc2[m][nt] = (floatx4){0.f, 0.f, 0.f, 0.f};

  const int arow = t >> 3, aseg = t & 7;
  const int sr = spkw[arow + 64];

  for (int kj = 0; kj < 192; kj += 32) {
    {
      u16 b0[4], b1[4], b2[4];
#pragma unroll
      for (int q = 0; q < 4; ++q) {
        int c = kj + aseg * 4 + q;
        u16 a = Am[arow * AMS + c];
        b0[q] = (c - arow >= 64) ? a : (u16)0;
        b1[q] = (spkw[c] == sr) ? a : (u16)0;
        b2[q] = a;
      }
      *(ushort4*)(B_ + (0 * 64 + arow) * 32 + aseg * 4) = *(const ushort4*)b0;
      *(ushort4*)(B_ + (2048 + arow * 32) + aseg * 4)   = *(const ushort4*)b1;
      *(ushort4*)(B_ + (4096 + arow * 32) + aseg * 4)   = *(const ushort4*)b2;
    }
    __syncthreads();

#pragma unroll
    for (int rel = 0; rel < 3; ++rel) {
      short8 af[4];
#pragma unroll
      for (int m = 0; m < 4; ++m)
        af[m] = *(const short8*)(B_ + rel * 2048 + (m * 16 + ln) * 32 + q8);
#pragma unroll
      for (int nt = 0; nt < 2; ++nt) {
        size_t so = (size_t)ST0 + (size_t)rel * STMAT
                  + (size_t)(n0 + nt * 16 + ln) * STROW + (i0 + kj) + q8;
        short8 bf8 = *(const short8*)(ws + so);
#pragma unroll
        for (int m = 0; m < 4; ++m)
          acc2[m][nt] = __builtin_amdgcn_mfma_f32_16x16x32_bf16(af[m], bf8, acc2[m][nt], 0, 0, 0);
      }
    }
    __syncthreads();
  }

  // ---- log_softmax over 256 dims ----
#pragma unroll
  for (int m = 0; m < 4; ++m)
#pragma unroll
    for (int r = 0; r < 4; ++r) {
      float v = fmaxf(acc2[m][0][r], acc2[m][1][r]);
#pragma unroll
      for (int o = 1; o < 16; o <<= 1) v = fmaxf(v, __shfl_xor(v, o));
      if (ln == 0) red[m * 16 + quad * 4 + r][w] = v;
    }
  __syncthreads();
  float gmx[4][4];
#pragma unroll
  for (int m = 0; m < 4; ++m)
#pragma unroll
    for (int r = 0; r < 4; ++r) {
      int row = m * 16 + quad * 4 + r;
      float g = red[row][0];
#pragma unroll
      for (int ww = 1; ww < 8; ++ww) g = fmaxf(g, red[row][ww]);
      gmx[m][r] = g;
    }
  __syncthreads();
#pragma unroll
  for (int m = 0; m < 4; ++m)
#pragma unroll
    for (int r = 0; r < 4; ++r) {
      float e = __expf(acc2[m][0][r] - gmx[m][r]) + __expf(acc2[m][1][r] - gmx[m][r]);
#pragma unroll
      for (int o = 1; o < 16; o <<= 1) e += __shfl_xor(e, o);
      if (ln == 0) red[m * 16 + quad * 4 + r][w] = e;
    }
  __syncthreads();
#pragma unroll
  for (int m = 0; m < 4; ++m)
#pragma unroll
    for (int r = 0; r < 4; ++r) {
      int row = m * 16 + quad * 4 + r;
      float s = red[row][0];
#pragma unroll
      for (int ww = 1; ww < 8; ++ww) s += red[row][ww];
      float lse = gmx[m][r] + logf(s);
      size_t rowg = (size_t)(i0 + row) * DIM;
      out[rowg + n0 + ln]      = acc2[m][0][r] - lse;
      out[rowg + n0 + 16 + ln] = acc2[m][1][r] - lse;
    }
}

extern "C" void kernel_launch(void* const* d_in, const int* in_sizes, int n_in,
                              void* d_out, int out_size, void* d_ws, size_t ws_size,
                              hipStream_t stream) {
  const float* x   = (const float*)d_in[0];
  const int*   spk = (const int*)d_in[1];
  const float* wat = (const float*)d_in[2];
  const float* wpr = (const float*)d_in[3];
  const float* wsu = (const float*)d_in[4];
  const float* wsm = (const float*)d_in[5];
  const float* wdf = (const float*)d_in[6];
  float* out = (float*)d_out;
  u16* ws = (u16*)d_ws;    // ~43 MB used

  void* args[] = {(void*)&x, (void*)&spk, (void*)&wat, (void*)&wpr,
                  (void*)&wsu, (void*)&wsm, (void*)&wdf, (void*)&out, (void*)&ws};
  hipLaunchCooperativeKernel((const void*)fused_all, dim3(256), dim3(512),
                             args, 0, stream);
}

// Round 8
// 190.821 us; speedup vs baseline: 1.6972x; 1.6972x over previous
//
#include <hip/hip_runtime.h>
#include <hip/hip_bf16.h>

typedef unsigned short u16;
typedef unsigned int u32;
typedef __attribute__((ext_vector_type(8))) short short8;
typedef __attribute__((ext_vector_type(4))) float floatx4;

#define NU 16384
#define DIM 256
#define AMS 208               // Am LDS row stride (u16)
#define XST 264               // gemmS strip stride (u16)

// ws layout (u16 offsets)
#define XHo 0u                // RNE-rounded hi (doubles as plain bf16 copy)
#define XLo 4194304u
#define YHo 8388608u
#define YLo 12582912u
#define ST0 16777216u
#define STROW 16512u          // 64 guard + 16384 + 64 guard
#define STMAT 4227072u        // 256 * STROW
#define WH0o 29458432u        // ST0 + 3*STMAT
#define WL0o 29523968u
#define WRo  29589504u        // 3 mats x 65536

__device__ __forceinline__ float bup(u16 u) {
  return __uint_as_float(((u32)u) << 16);
}
__device__ __forceinline__ u16 bfrn(float v) {           // round-nearest-even
  u32 u = __float_as_uint(v);
  return (u16)((u + 0x7fffu + ((u >> 16) & 1u)) >> 16);
}

// ---------------------------------------------------------------------------
// prep: b<2048 x-split (hi=RNE, lo=residual); b<2064 weight imaging
// ([s][n][k] order); b<2160 S^T guard zeroing.
// ---------------------------------------------------------------------------
__global__ __launch_bounds__(256) void prep(
    const float* __restrict__ x,
    const float* __restrict__ wat, const float* __restrict__ wpr,
    const float* __restrict__ wsu, const float* __restrict__ wsm,
    const float* __restrict__ wdf, u16* __restrict__ ws) {
  const int b = blockIdx.x, t = threadIdx.x;
  if (b < 2048) {
    int idx = (b * 256 + t) * 8;
    float4 v0 = *(const float4*)(x + idx);
    float4 v1 = *(const float4*)(x + idx + 4);
    float a[8] = {v0.x, v0.y, v0.z, v0.w, v1.x, v1.y, v1.z, v1.w};
    u16 h[8], l[8];
#pragma unroll
    for (int q = 0; q < 8; ++q) {
      h[q] = bfrn(a[q]);
      l[q] = bfrn(a[q] - bup(h[q]));
    }
    *(uint4*)(ws + XHo + idx) = *(const uint4*)h;
    *(uint4*)(ws + XLo + idx) = *(const uint4*)l;
  } else if (b < 2064) {
    const int bp = b - 2048;
    const int mat = bp >> 2, n = t;
    const float* Wa = (mat == 0) ? wat : (mat == 1) ? wpr : (mat == 2) ? wsm : wsu;
    const float* Wb = (mat == 0) ? wat : (mat == 1) ? wsu : (mat == 2) ? wdf : wdf;
    const float c1  = (mat == 0) ? 0.f : (mat == 3) ? 1.f : -1.f;
    for (int si = 0; si < 2; ++si) {
      const int s = (bp & 3) * 2 + si;
      u16 hbuf[32], lbuf[32];
#pragma unroll 8
      for (int k = 0; k < 32; ++k) {
        float v = Wa[(s * 32 + k) * 256 + n] + c1 * Wb[(s * 32 + k) * 256 + n];
        hbuf[k] = bfrn(v);
        if (mat == 0) lbuf[k] = bfrn(v - bup(hbuf[k]));
      }
      u16* dh = ws + ((mat == 0) ? WH0o : (WRo + (size_t)(mat - 1) * 65536))
                 + (size_t)s * 8192 + n * 32;
#pragma unroll
      for (int p = 0; p < 4; ++p) *(uint4*)(dh + p * 8) = ((const uint4*)hbuf)[p];
      if (mat == 0) {
        u16* dl = ws + WL0o + (size_t)s * 8192 + n * 32;
#pragma unroll
        for (int p = 0; p < 4; ++p) *(uint4*)(dl + p * 8) = ((const uint4*)lbuf)[p];
      }
    }
  } else {
    int g = (b - 2064) * 256 + t;                  // 0..24575
    int r = g >> 13, rem = g & 8191;
    int d = rem >> 5, p = rem & 31;
    size_t base = ST0 + (size_t)r * STMAT + (size_t)d * STROW;
    size_t off = (p < 16) ? (base + p * 4) : (base + 16448 + (p - 16) * 4);
    *(ushort4*)(ws + off) = make_ushort4(0, 0, 0, 0);
  }
}

// ---------------------------------------------------------------------------
// gemmS: grid (256, 2), 512 thr. path0: y=x@W_att split 3-MFMA -> yh/yl.
// path1: S1..S3 single-MFMA -> S^T (transposed epilogue). A-strip staged
// once (stride 264); W fragments direct from L2-resident images.
// ---------------------------------------------------------------------------
__global__ __launch_bounds__(512) void gemmS(u16* __restrict__ ws) {
  __shared__ __align__(16) u16 U[37888];   // p0: Ah@0 Al@16896 ; p1: Ah@0 Ct@16896

  const int t = threadIdx.x, path = blockIdx.y, row0 = blockIdx.x * 64;
  const int w = t >> 6, ln = t & 15, quad = (t & 63) >> 4, q8 = quad * 8;
  const int n0 = w * 32;

  if (path == 0) {
#pragma unroll
    for (int cc = 0; cc < 8; ++cc) {
      int idx = t + 512 * cc;                  // 0..4095
      int buf = idx >> 11, e = idx & 2047;
      int row = e >> 5, c8 = (e & 31) * 8;
      *(uint4*)(U + buf * 16896 + row * XST + c8) =
          *(const uint4*)(ws + (buf ? XLo : XHo) + (size_t)(row0 + row) * 256 + c8);
    }
    __syncthreads();

    floatx4 acc[4][2];
#pragma unroll
    for (int m = 0; m < 4; ++m)
#pragma unroll
      for (int nt = 0; nt < 2; ++nt) acc[m][nt] = (floatx4){0.f, 0.f, 0.f, 0.f};

    for (int s = 0; s < 8; ++s) {
      short8 ah[4], al[4];
#pragma unroll
      for (int m = 0; m < 4; ++m) {
        ah[m] = *(const short8*)(U + (m * 16 + ln) * XST + s * 32 + q8);
        al[m] = *(const short8*)(U + 16896 + (m * 16 + ln) * XST + s * 32 + q8);
      }
      short8 bh[2], bl[2];
#pragma unroll
      for (int nt = 0; nt < 2; ++nt) {
        size_t off = (size_t)s * 8192 + (n0 + nt * 16 + ln) * 32 + q8;
        bh[nt] = *(const short8*)(ws + WH0o + off);
        bl[nt] = *(const short8*)(ws + WL0o + off);
      }
#pragma unroll
      for (int m = 0; m < 4; ++m)
#pragma unroll
        for (int nt = 0; nt < 2; ++nt) {
          acc[m][nt] = __builtin_amdgcn_mfma_f32_16x16x32_bf16(ah[m], bh[nt], acc[m][nt], 0, 0, 0);
          acc[m][nt] = __builtin_amdgcn_mfma_f32_16x16x32_bf16(ah[m], bl[nt], acc[m][nt], 0, 0, 0);
          acc[m][nt] = __builtin_amdgcn_mfma_f32_16x16x32_bf16(al[m], bh[nt], acc[m][nt], 0, 0, 0);
        }
    }
#pragma unroll
    for (int m = 0; m < 4; ++m)
#pragma unroll
      for (int nt = 0; nt < 2; ++nt) {
        int col = n0 + nt * 16 + ln;
#pragma unroll
        for (int r = 0; r < 4; ++r) {
          int row = row0 + m * 16 + quad * 4 + r;
          float y = acc[m][nt][r];
          u16 hh = bfrn(y);
          ws[YHo + (size_t)row * 256 + col] = hh;
          ws[YLo + (size_t)row * 256 + col] = bfrn(y - bup(hh));
        }
      }
  } else {
#pragma unroll
    for (int cc = 0; cc < 4; ++cc) {
      int idx = t + 512 * cc;                  // 0..2047
      int row = idx >> 5, c8 = (idx & 31) * 8;
      *(uint4*)(U + row * XST + c8) =
          *(const uint4*)(ws + XHo + (size_t)(row0 + row) * 256 + c8);
    }
    __syncthreads();

    for (int mat = 0; mat < 3; ++mat) {
      floatx4 acc[4][2];
#pragma unroll
      for (int m = 0; m < 4; ++m)
#pragma unroll
        for (int nt = 0; nt < 2; ++nt) acc[m][nt] = (floatx4){0.f, 0.f, 0.f, 0.f};
      for (int s = 0; s < 8; ++s) {
        short8 ah[4];
#pragma unroll
        for (int m = 0; m < 4; ++m)
          ah[m] = *(const short8*)(U + (m * 16 + ln) * XST + s * 32 + q8);
        short8 bh[2];
#pragma unroll
        for (int nt = 0; nt < 2; ++nt)
          bh[nt] = *(const short8*)(ws + WRo + (size_t)mat * 65536
                                    + (size_t)s * 8192 + (n0 + nt * 16 + ln) * 32 + q8);
#pragma unroll
        for (int m = 0; m < 4; ++m)
#pragma unroll
          for (int nt = 0; nt < 2; ++nt)
            acc[m][nt] = __builtin_amdgcn_mfma_f32_16x16x32_bf16(ah[m], bh[nt], acc[m][nt], 0, 0, 0);
      }
      __syncthreads();                           // Ct reuse guard
#pragma unroll
      for (int m = 0; m < 4; ++m)
#pragma unroll
        for (int nt = 0; nt < 2; ++nt) {
          int col = n0 + nt * 16 + ln;
          ushort4 pk = make_ushort4(bfrn(acc[m][nt][0]), bfrn(acc[m][nt][1]),
                                    bfrn(acc[m][nt][2]), bfrn(acc[m][nt][3]));
          *(ushort4*)(U + 16896 + col * 80 + m * 16 + quad * 4) = pk;
        }
      __syncthreads();
      u16* STm = ws + ST0 + (size_t)mat * STMAT;
#pragma unroll
      for (int cc = 0; cc < 4; ++cc) {
        int c = t + 512 * cc;
        int d = c >> 3, part = c & 7;
        *(uint4*)(STm + (size_t)d * STROW + 64 + row0 + part * 8) =
            *(const uint4*)(U + 16896 + d * 80 + part * 8);
      }
    }
  }
}

// ---------------------------------------------------------------------------
// fused_attn: 64 utterances/block, 1024 thr (16 waves/CU), grid 256.
// ph1: P = Y.Xwin^T (X staged per k-step; Y frags direct global; P in regs).
// softmax in registers (2 small LDS exchanges); bf16 A-image in LDS.
// ph2: masked Ac chunks + direct-global S^T B-frags (16 n-frags).
// cross-wave log_softmax; fp32 out.
// ---------------------------------------------------------------------------
__global__ __launch_bounds__(1024) void fused_attn(
    const u16* __restrict__ ws, const int* __restrict__ spk,
    float* __restrict__ out)
{
  __shared__ __align__(16) u16 B_[12288];     // ph1: Xh@0 Xl@6144 ; ph2: Ac[3][64][32]
  __shared__ __align__(16) u16 Am[64 * AMS];
  __shared__ int spkw[192];
  __shared__ float prt[64][4], prs[64][4];
  __shared__ float red[64][16];

  const int t    = threadIdx.x;
  const int w    = t >> 6;                     // 0..15
  const int ln   = t & 15;
  const int quad = (t & 63) >> 4;
  const int q8   = quad * 8;
  const int i0   = blockIdx.x * 64;
  const int mw   = w & 3;                      // m-frag (16 rows)
  const int cg   = w >> 2;                     // col-group (48 cols each)

  if (t < 192) spkw[t] = spk[min(max(i0 - 64 + t, 0), NU - 1)];

  // ---------------- Phase 1: P = Y . Xwin^T ----------------
  floatx4 accP[3];
#pragma unroll
  for (int cc = 0; cc < 3; ++cc) accP[cc] = (floatx4){0.f, 0.f, 0.f, 0.f};

  for (int kd = 0; kd < DIM; kd += 32) {
    {                                           // stage X window 192x32 hi/lo
      int idx = t;                              // 0..1023
      int buf = (idx >= 768) ? 1 : 0;
      int e   = idx - buf * 768;
      int row = e >> 2, c8 = (e & 3) * 8;
      int jc  = min(max(i0 + row - 64, 0), NU - 1);
      *(uint4*)(B_ + buf * 6144 + row * 32 + c8) =
          *(const uint4*)(ws + (buf ? XLo : XHo) + (size_t)jc * 256 + kd + c8);
      if (t < 512) {
        idx = t + 1024;                         // 1024..1535 (all buf=1)
        e   = idx - 768;
        row = e >> 2; c8 = (e & 3) * 8;
        jc  = min(max(i0 + row - 64, 0), NU - 1);
        *(uint4*)(B_ + 6144 + row * 32 + c8) =
            *(const uint4*)(ws + XLo + (size_t)jc * 256 + kd + c8);
      }
    }
    __syncthreads();

    size_t yo = (size_t)(i0 + mw * 16 + ln) * 256 + kd + q8;
    short8 yh8 = *(const short8*)(ws + YHo + yo);
    short8 yl8 = *(const short8*)(ws + YLo + yo);
#pragma unroll
    for (int cc = 0; cc < 3; ++cc) {
      int xrow = (cg * 3 + cc) * 16 + ln;
      short8 xbh = *(const short8*)(B_ + xrow * 32 + q8);
      short8 xbl = *(const short8*)(B_ + 6144 + xrow * 32 + q8);
      accP[cc] = __builtin_amdgcn_mfma_f32_16x16x32_bf16(yh8, xbh, accP[cc], 0, 0, 0);
      accP[cc] = __builtin_amdgcn_mfma_f32_16x16x32_bf16(yh8, xbl, accP[cc], 0, 0, 0);
      accP[cc] = __builtin_amdgcn_mfma_f32_16x16x32_bf16(yl8, xbh, accP[cc], 0, 0, 0);
    }
    __syncthreads();
  }

  // ---------------- Softmax in registers ----------------
  int  c_of[3];
  bool vj[3];
#pragma unroll
  for (int cc = 0; cc < 3; ++cc) {
    c_of[cc] = (cg * 3 + cc) * 16 + ln;
    int j = i0 + c_of[cc] - 64;
    vj[cc] = (j >= 0) && (j < NU);
  }
#pragma unroll
  for (int r = 0; r < 4; ++r) {
    int row = mw * 16 + quad * 4 + r;
    float mx = -3.4e38f;
#pragma unroll
    for (int cc = 0; cc < 3; ++cc) {
      int rel = c_of[cc] - row;
      bool inb = (rel >= 0) && (rel < 128);
      if (inb) mx = fmaxf(mx, vj[cc] ? accP[cc][r] : 0.f);
    }
#pragma unroll
    for (int o = 1; o < 16; o <<= 1) mx = fmaxf(mx, __shfl_xor(mx, o));
    if (ln == 0) prt[row][cg] = mx;
  }
  __syncthreads();
#pragma unroll
  for (int r = 0; r < 4; ++r) {
    int row = mw * 16 + quad * 4 + r;
    float gm = fmaxf(fmaxf(prt[row][0], prt[row][1]),
                     fmaxf(prt[row][2], prt[row][3]));
    float s = 0.f;
#pragma unroll
    for (int cc = 0; cc < 3; ++cc) {
      int rel = c_of[cc] - row;
      bool inb = (rel >= 0) && (rel < 128);
      float vv = vj[cc] ? accP[cc][r] : 0.f;
      float e  = inb ? __expf(vv - gm) : 0.f;
      s += e;                                    // padded-slot denominator
      accP[cc][r] = (inb && vj[cc]) ? e : 0.f;   // masked numerator
    }
#pragma unroll
    for (int o = 1; o < 16; o <<= 1) s += __shfl_xor(s, o);
    if (ln == 0) prs[row][cg] = s;
  }
  __syncthreads();
#pragma unroll
  for (int r = 0; r < 4; ++r) {
    int row = mw * 16 + quad * 4 + r;
    float inv = 1.f / (prs[row][0] + prs[row][1] + prs[row][2] + prs[row][3]);
#pragma unroll
    for (int cc = 0; cc < 3; ++cc)
      Am[row * AMS + c_of[cc]] = bfrn(accP[cc][r] * inv);
  }
  __syncthreads();

  // ---------------- Phase 2: aggregation ----------------
  const int n0 = w * 16;                        // 16 dims per wave
  floatx4 acc2[4];
#pragma unroll
  for (int m = 0; m < 4; ++m) acc2[m] = (floatx4){0.f, 0.f, 0.f, 0.f};

  const int arow = t >> 3, aseg = t & 7;        // builders: t < 512
  const int sr = (t < 512) ? spkw[arow + 64] : 0;

  for (int kj = 0; kj < 192; kj += 32) {
    if (t < 512) {
      u16 b0[4], b1[4], b2[4];
#pragma unroll
      for (int q = 0; q < 4; ++q) {
        int c = kj + aseg * 4 + q;
        u16 a = Am[arow * AMS + c];
        b0[q] = (c - arow >= 64) ? a : (u16)0;
        b1[q] = (spkw[c] == sr) ? a : (u16)0;
        b2[q] = a;
      }
      *(ushort4*)(B_ + (0 * 64 + arow) * 32 + aseg * 4) = *(const ushort4*)b0;
      *(ushort4*)(B_ + (2048 + arow * 32) + aseg * 4)   = *(const ushort4*)b1;
      *(ushort4*)(B_ + (4096 + arow * 32) + aseg * 4)   = *(const ushort4*)b2;
    }
    __syncthreads();

#pragma unroll
    for (int rel = 0; rel < 3; ++rel) {
      short8 af[4];
#pragma unroll
      for (int m = 0; m < 4; ++m)
        af[m] = *(const short8*)(B_ + rel * 2048 + (m * 16 + ln) * 32 + q8);
      size_t so = (size_t)ST0 + (size_t)rel * STMAT
                + (size_t)(n0 + ln) * STROW + (i0 + kj) + q8;
      short8 bf8 = *(const short8*)(ws + so);
#pragma unroll
      for (int m = 0; m < 4; ++m)
        acc2[m] = __builtin_amdgcn_mfma_f32_16x16x32_bf16(af[m], bf8, acc2[m], 0, 0, 0);
    }
    __syncthreads();
  }

  // ---------------- log_softmax over 256 dims ----------------
#pragma unroll
  for (int m = 0; m < 4; ++m)
#pragma unroll
    for (int r = 0; r < 4; ++r) {
      float v = acc2[m][r];
#pragma unroll
      for (int o = 1; o < 16; o <<= 1) v = fmaxf(v, __shfl_xor(v, o));
      if (ln == 0) red[m * 16 + quad * 4 + r][w] = v;
    }
  __syncthreads();
  float gmx[4][4];
#pragma unroll
  for (int m = 0; m < 4; ++m)
#pragma unroll
    for (int r = 0; r < 4; ++r) {
      int row = m * 16 + quad * 4 + r;
      float g = red[row][0];
#pragma unroll
      for (int ww = 1; ww < 16; ++ww) g = fmaxf(g, red[row][ww]);
      gmx[m][r] = g;
    }
  __syncthreads();
#pragma unroll
  for (int m = 0; m < 4; ++m)
#pragma unroll
    for (int r = 0; r < 4; ++r) {
      float e = __expf(acc2[m][r] - gmx[m][r]);
#pragma unroll
      for (int o = 1; o < 16; o <<= 1) e += __shfl_xor(e, o);
      if (ln == 0) red[m * 16 + quad * 4 + r][w] = e;
    }
  __syncthreads();
#pragma unroll
  for (int m = 0; m < 4; ++m)
#pragma unroll
    for (int r = 0; r < 4; ++r) {
      int row = m * 16 + quad * 4 + r;
      float s = red[row][0];
#pragma unroll
      for (int ww = 1; ww < 16; ++ww) s += red[row][ww];
      float lse = gmx[m][r] + logf(s);
      out[(size_t)(i0 + row) * DIM + n0 + ln] = acc2[m][r] - lse;
    }
}

extern "C" void kernel_launch(void* const* d_in, const int* in_sizes, int n_in,
                              void* d_out, int out_size, void* d_ws, size_t ws_size,
                              hipStream_t stream) {
  const float* x   = (const float*)d_in[0];
  const int*   spk = (const int*)d_in[1];
  const float* wat = (const float*)d_in[2];
  const float* wpr = (const float*)d_in[3];
  const float* wsu = (const float*)d_in[4];
  const float* wsm = (const float*)d_in[5];
  const float* wdf = (const float*)d_in[6];
  float* out = (float*)d_out;
  u16* ws = (u16*)d_ws;    // ~60 MB used

  hipLaunchKernelGGL(prep, dim3(2160), dim3(256), 0, stream,
                     x, wat, wpr, wsu, wsm, wdf, ws);
  hipLaunchKernelGGL(gemmS, dim3(256, 2), dim3(512), 0, stream, ws);
  hipLaunchKernelGGL(fused_attn, dim3(256), dim3(1024), 0, stream, ws, spk, out);
}